// Round 9
// baseline (51.147 us; speedup 1.0000x reference)
//
#include <hip/hip_runtime.h>
#include <math.h>

// Analytic collapse (verified R1-R8, absmax 3.9e-3):
//   t = tanh(W1 @ x_n); v = tanh(W2 @ t); z = Wout . v
//   a = sum_h sob[h]*sin(2*pi*soa[h]*z/7);  out = sign(a)*4*z*e^|a|/(4e^|a|+5)
//
// R9: identical fp32-emulated MFMA arithmetic (bf16 3-level split, 6 products
// per accumulator, same order -> bit-identical to R4-R8). Schedule:
//   - 24 uniform phases (16 L1 + 8 L2), ONE barrier per phase.
//   - per phase: issue next 12 KB A-batch via global_load_lds into the
//     alternate buffer; counted vmcnt(5)/vmcnt(3) (never 0 mid-loop);
//     pack B from regs; setprio(1) around the 24-MFMA cluster.
//   - 256-thr blocks (4 waves, 128 rows), grid=512 -> 2 INDEPENDENT blocks/CU
//     (24 KB LDS each) whose drift provides cross-block stage||MFMA overlap.

typedef __bf16 bf16x8 __attribute__((ext_vector_type(8)));
typedef float  f32x16 __attribute__((ext_vector_type(16)));
typedef unsigned int u32;
typedef unsigned short u16;

union FRAG { uint4 q; bf16x8 v; };

#define NROWS 65536

// ---- bf16 3-level split: x = h + m + l + O(2^-25 |x|) ----
__device__ __forceinline__ void split3(float x, u32& h, u32& m, u32& l) {
    u32 u = __float_as_uint(x);
    h = u >> 16;
    float hf = __uint_as_float(u & 0xFFFF0000u);
    float r1 = x - hf;                       // exact
    u32 u1 = __float_as_uint(r1);
    m = u1 >> 16;
    float mf = __uint_as_float(u1 & 0xFFFF0000u);
    float r2 = r1 - mf;                      // exact
    u32 u2 = __float_as_uint(r2);
    l = (u2 + 0x7FFFu + ((u2 >> 16) & 1u)) >> 16;   // RNE
}

__device__ __forceinline__ void pack2(float a, float b, u32& H, u32& M, u32& L) {
    u32 h0, m0, l0, h1, m1, l1;
    split3(a, h0, m0, l0); split3(b, h1, m1, l1);
    H = h0 | (h1 << 16); M = m0 | (m1 << 16); L = l0 | (l1 << 16);
}

__device__ __forceinline__ float fast_tanh(float x) {
    float e = __expf(2.f * x);
    return 1.f - 2.f * __builtin_amdgcn_rcpf(e + 1.f);  // inf-safe, ~4e-7 abs err
}

__device__ __forceinline__ void glds16(const uint4* g, uint4* l) {
    __builtin_amdgcn_global_load_lds(
        (const __attribute__((address_space(1))) void*)g,
        (__attribute__((address_space(3))) void*)l, 16, 0, 0);
}

// ====== pre-kernel: split W1/W2 into fragment-major bf16 planes in d_ws ======
// uint4 units: L1 frag f=g*4+ot, levels at 0/4096/8192, idx=lv*4096+f*64+lane
//              L2 frag f2=s*4+ot, at 12288+lv*2048+f2*64+lane
__global__ void presplit(const float* __restrict__ W1,
                         const float* __restrict__ W2,
                         u16* __restrict__ ws)
{
    int t = blockIdx.x * 256 + threadIdx.x;   // 0..6143
    const float* src;
    size_t dbase, lstep;
    if (t < 4096) {
        int f = t >> 6, lane = t & 63;
        int c = f >> 4, s = (f >> 2) & 3, ot = f & 3;
        int l31 = lane & 31, hi = lane >> 5;
        src   = W1 + (size_t)(32 * ot + l31) * 256 + c * 64 + s * 16 + 8 * hi;
        dbase = (size_t)(f * 64 + lane) * 8;
        lstep = 32768;
    } else {
        int t2 = t - 4096;
        int f = t2 >> 6, lane = t2 & 63;
        int s = f >> 2, ot = f & 3;
        int l31 = lane & 31, hi = lane >> 5;
        src   = W2 + (size_t)(32 * ot + l31) * 128 + s * 16 + 8 * hi;
        dbase = 98304 + (size_t)(f * 64 + lane) * 8;
        lstep = 16384;
    }
    u16 H[8], M[8], L[8];
    #pragma unroll
    for (int j = 0; j < 8; ++j) {
        u32 h, m, l;
        split3(src[j], h, m, l);
        H[j] = (u16)h; M[j] = (u16)m; L[j] = (u16)l;
    }
    #pragma unroll
    for (int j = 0; j < 8; ++j) {
        ws[dbase + j]             = H[j];
        ws[dbase + lstep + j]     = M[j];
        ws[dbase + 2 * lstep + j] = L[j];
    }
}

// ================= main kernel ==============================================
// 256 thr = 4 waves; 128 rows/block; wave w owns rows 32w..32w+31; grid = 512.
__global__ __launch_bounds__(256, 2)
void fused_mlp9(const float* __restrict__ x,
                const u16*   __restrict__ wsp,
                const float* __restrict__ Wout,
                const float* __restrict__ soa,
                const float* __restrict__ sob,
                float* __restrict__ out)
{
    __shared__ uint4 Ab[2][768];              // 24 KB A-batch double buffer

    const int tid  = threadIdx.x;
    const int w    = tid >> 6;                // 0..3
    const int lane = tid & 63;
    const int l31  = lane & 31;
    const int hi   = lane >> 5;
    const int nloc = (w << 5) + l31;          // this lane's local row
    const int n0g  = blockIdx.x * 128;

    const uint4*  wf   = reinterpret_cast<const uint4*>(wsp);
    const float4* xrow = reinterpret_cast<const float4*>(x) + (size_t)(n0g + nloc) * 64;

    // wave w stages items i = 3w..3w+2 (of 12) of K16-step g's A-batch
    auto stage = [&](int g, uint4* dst) {
        #pragma unroll
        for (int j = 0; j < 3; ++j) {
            int i  = w * 3 + j;               // 0..11
            int lv = i >> 2, ot = i & 3;
            const uint4* src = (g < 16)
                ? wf + lv * 4096 + (g * 4 + ot) * 64 + lane
                : wf + 12288 + lv * 2048 + ((g - 16) * 4 + ot) * 64 + lane;
            glds16(src, dst + i * 64);
        }
    };

    f32x16 acc[4];
    #pragma unroll
    for (int ot = 0; ot < 4; ++ot) acc[ot] = (f32x16)0.f;

    // MFMA cluster for one K16-step (6 products per acc, fixed order)
    auto cluster = [&](const uint4* Ac, f32x16* A,
                       const FRAG& Bh, const FRAG& Bm, const FRAG& Bl) {
        __builtin_amdgcn_s_setprio(1);
        #pragma unroll
        for (int ot = 0; ot < 4; ++ot) {
            FRAG Ah, Am, Al;
            Ah.q = Ac[ot * 64 + lane];
            Am.q = Ac[(4 + ot) * 64 + lane];
            Al.q = Ac[(8 + ot) * 64 + lane];
            A[ot] = __builtin_amdgcn_mfma_f32_32x32x16_bf16(Ah.v, Bh.v, A[ot], 0,0,0);
            A[ot] = __builtin_amdgcn_mfma_f32_32x32x16_bf16(Ah.v, Bm.v, A[ot], 0,0,0);
            A[ot] = __builtin_amdgcn_mfma_f32_32x32x16_bf16(Am.v, Bh.v, A[ot], 0,0,0);
            A[ot] = __builtin_amdgcn_mfma_f32_32x32x16_bf16(Am.v, Bm.v, A[ot], 0,0,0);
            A[ot] = __builtin_amdgcn_mfma_f32_32x32x16_bf16(Ah.v, Bl.v, A[ot], 0,0,0);
            A[ot] = __builtin_amdgcn_mfma_f32_32x32x16_bf16(Al.v, Bh.v, A[ot], 0,0,0);
        }
        __builtin_amdgcn_s_setprio(0);
    };

    auto packB = [&](const float4& a, const float4& b, FRAG& Bh, FRAG& Bm, FRAG& Bl) {
        pack2(a.x, a.y, Bh.q.x, Bm.q.x, Bl.q.x);
        pack2(a.z, a.w, Bh.q.y, Bm.q.y, Bl.q.y);
        pack2(b.x, b.y, Bh.q.z, Bm.q.z, Bl.q.z);
        pack2(b.z, b.w, Bh.q.w, Bm.q.w, Bl.q.w);
    };

    // ---- prologue: A(0) -> buf0; x(0) ----
    stage(0, Ab[0]);
    float4 xA0 = xrow[hi * 2], xA1 = xrow[hi * 2 + 1];

    // =================== layer 1: 16 phases (2 per iteration) ================
    #pragma unroll 1
    for (int gp = 0; gp < 8; ++gp) {
        // ---- phase g = 2gp (even -> reads buf0), loads x(2gp+1) ----
        asm volatile("s_barrier" ::: "memory");
        stage(2 * gp + 1, Ab[1]);
        float4 xB0, xB1;
        {
            int gn = 2 * gp + 1;
            xB0 = xrow[gn * 4 + hi * 2];
            xB1 = xrow[gn * 4 + hi * 2 + 1];
        }
        asm volatile("s_waitcnt vmcnt(5)" ::: "memory");   // A(2gp)+x(2gp) landed
        __builtin_amdgcn_sched_barrier(0);
        {
            FRAG Bh, Bm, Bl;
            packB(xA0, xA1, Bh, Bm, Bl);
            cluster(Ab[0], acc, Bh, Bm, Bl);
        }

        // ---- phase g = 2gp+1 (odd -> reads buf1), loads x(2gp+2) ----
        asm volatile("s_barrier" ::: "memory");
        stage(2 * gp + 2, Ab[0]);                          // gp=7 -> stage(16)
        if (gp < 7) {
            int gn = 2 * gp + 2;
            xA0 = xrow[gn * 4 + hi * 2];
            xA1 = xrow[gn * 4 + hi * 2 + 1];
        }
        asm volatile("s_waitcnt vmcnt(5)" ::: "memory");
        __builtin_amdgcn_sched_barrier(0);
        {
            FRAG Bh, Bm, Bl;
            packB(xB0, xB1, Bh, Bm, Bl);
            cluster(Ab[1], acc, Bh, Bm, Bl);
        }
    }

    // ====== t = tanh(D1); build layer-2 B-frags in registers (3 planes) ======
    FRAG tf[3][8];
    #pragma unroll
    for (int ft = 0; ft < 4; ++ft) {
        #pragma unroll
        for (int sub = 0; sub < 2; ++sub) {
            int s = 2 * ft + sub;
            float tv[8];
            u32 th[8], tm[8], tlv[8];
            #pragma unroll
            for (int j = 0; j < 8; ++j) {
                tv[j] = fast_tanh(acc[ft][8 * sub + j]);
                split3(tv[j], th[j], tm[j], tlv[j]);
            }
            #pragma unroll
            for (int lv = 0; lv < 3; ++lv) {
                const u32* t_ = (lv == 0) ? th : (lv == 1) ? tm : tlv;
                u32 P0 = t_[0] | (t_[1] << 16);
                u32 P1 = t_[2] | (t_[3] << 16);
                u32 Q0 = t_[4] | (t_[5] << 16);
                u32 Q1 = t_[6] | (t_[7] << 16);
                u32 sP0 = (u32)__shfl_xor((int)P0, 32);
                u32 sP1 = (u32)__shfl_xor((int)P1, 32);
                u32 sQ0 = (u32)__shfl_xor((int)Q0, 32);
                u32 sQ1 = (u32)__shfl_xor((int)Q1, 32);
                tf[lv][s].q.x = hi ? sQ0 : P0;
                tf[lv][s].q.y = hi ? sQ1 : P1;
                tf[lv][s].q.z = hi ? Q0 : sP0;
                tf[lv][s].q.w = hi ? Q1 : sP1;
            }
        }
    }

    // =================== layer 2: 8 phases (fully unrolled) ==================
    f32x16 acc2[4];
    #pragma unroll
    for (int ot = 0; ot < 4; ++ot) acc2[ot] = (f32x16)0.f;

    #pragma unroll
    for (int s = 0; s < 8; ++s) {
        asm volatile("s_barrier" ::: "memory");
        if (s < 7) {
            stage(17 + s, Ab[(17 + s) & 1]);
            asm volatile("s_waitcnt vmcnt(3)" ::: "memory");  // A(16+s) landed
        } else {
            asm volatile("s_waitcnt vmcnt(0)" ::: "memory");  // last batch
        }
        __builtin_amdgcn_sched_barrier(0);
        cluster(Ab[(16 + s) & 1], acc2, tf[0][s], tf[1][s], tf[2][s]);
    }

    // ====== epilogue: v = tanh(D2); z = Wout . v ; analytic tail ======
    float zp = 0.f;
    #pragma unroll
    for (int ft = 0; ft < 4; ++ft) {
        #pragma unroll
        for (int rg = 0; rg < 4; ++rg) {
            const float4 wo = *reinterpret_cast<const float4*>(Wout + 32 * ft + 8 * rg + 4 * hi);
            zp += fast_tanh(acc2[ft][4 * rg + 0]) * wo.x
                + fast_tanh(acc2[ft][4 * rg + 1]) * wo.y
                + fast_tanh(acc2[ft][4 * rg + 2]) * wo.z
                + fast_tanh(acc2[ft][4 * rg + 3]) * wo.w;
        }
    }
    float z = zp + __shfl_xor(zp, 32);

    if (lane < 32) {
        const float CC = 0.8975979010256552f;   // 2*pi/7
        float a = 0.f;
        #pragma unroll
        for (int k = 0; k < 32; ++k)
            a += sob[k] * sinf(CC * soa[k] * z);
        float mm  = expf(fabsf(a));
        float res = 4.f * z * mm / (4.f * mm + 5.f);
        out[n0g + (w << 5) + lane] = (a > 0.f) ? res : ((a < 0.f) ? -res : 0.f);
    }
}

extern "C" void kernel_launch(void* const* d_in, const int* in_sizes, int n_in,
                              void* d_out, int out_size, void* d_ws, size_t ws_size,
                              hipStream_t stream) {
    const float* x    = (const float*)d_in[0];
    const float* W1   = (const float*)d_in[1];
    const float* W2   = (const float*)d_in[2];
    const float* Wout = (const float*)d_in[3];
    const float* soa  = (const float*)d_in[8];
    const float* sob  = (const float*)d_in[9];
    float* outp = (float*)d_out;
    u16* ws = (u16*)d_ws;   // needs 294912 B

    hipLaunchKernelGGL(presplit, dim3(24), dim3(256), 0, stream, W1, W2, ws);
    hipLaunchKernelGGL(fused_mlp9, dim3(NROWS / 128), dim3(256), 0, stream,
                       x, ws, Wout, soa, sob, outp);
}